// Round 7
// baseline (653.375 us; speedup 1.0000x reference)
//
#include <hip/hip_runtime.h>

// EdgeConv: B=4, C=64, N=8192, K=16, COUT=64, fp32.
// ws layout (27.6 MB, cpack aliased onto mnb):
//   xt    : 0         (B*N*C f32 = 8388608 B)   x transposed to (B,N,C)
//   knn   : 8388608   (B*N*16 i32 = 2097152 B)
//   mnb   : 10485760  (B*N*64 f32 = 8388608 B)  min_k h   [cpack aliases here first]
//   mxb   : 18874368  (B*N*64 f32 = 8388608 B)  max_k h
//   ps1   : 27262976  (512*64 f32)
//   ps2   : 27394048  (512*64 f32)
//   stats : 27525120  (128 f32)

#define Bn 4
#define Cn 64
#define Nn 8192
#define Kn 16
#define CH 32
#define NSL 8   // slices per query

typedef unsigned long long ull;

// ------- transpose x (B,C,N) -> xt (B,N,C); also pack coords -> (x,y,z,sq) -------
__global__ __launch_bounds__(256) void transpose_kernel(const float* __restrict__ x,
                                                        const float* __restrict__ coords,
                                                        float* __restrict__ xt,
                                                        float4* __restrict__ cpack) {
  __shared__ float tile[64][65];
  int bid = blockIdx.x;          // 512 = B * (N/64)
  int b = bid >> 7;
  int n0 = (bid & 127) << 6;
  int tx = threadIdx.x & 63;
  int ty = threadIdx.x >> 6;
  for (int c = ty; c < 64; c += 4)
    tile[tx][c] = x[((size_t)b * 64 + c) * Nn + n0 + tx];
  if (ty == 0) {
    int n = n0 + tx;
    const float* cb = coords + (size_t)b * 3 * Nn;
    float cx = cb[n], cy = cb[Nn + n], cz = cb[2 * Nn + n];
    // sq exactly as np.sum(ct*ct,-1): ((x*x + y*y) + z*z), no FMA
    float cs = __fadd_rn(__fadd_rn(__fmul_rn(cx, cx), __fmul_rn(cy, cy)),
                         __fmul_rn(cz, cz));
    cpack[(size_t)b * Nn + n] = make_float4(cx, cy, cz, cs);
  }
  __syncthreads();
  for (int r = ty; r < 64; r += 4)
    xt[((size_t)b * Nn + n0 + r) * 64 + tx] = tile[r][tx];
}

// ---------------- brute-force KNN (top-16 excluding self) ----------------
// d2 EXACTLY like the reference: (sq_n + sq_m) - 2*dot, non-contracted f32
// (2*dot via pre-doubled query coords: pow2 scale commutes with rounding).
// Key = (f32_bits(d2)<<32)|idx: stable lowest-index tie-break like lax.top_k.
// Self excluded by clearing its mask bit (1 instr/chunk) -- same semantics as
// the r5 PASSING kernel (top-16, m != qg).
//
// Structure: 512 blocks = B*(N/64); 512 threads = 64 queries x 8 slices
// (wave = one slice, all 64 queries). Hot loop: broadcast float4 load +
// 7 exact VALU + cmp -> accept bit in a u32 mask (no stores, no exec
// juggling). Rare flush rescans accepted candidates (ffs over mask),
// recomputes d2 bit-identically, exact u64 16-deep sorted insert,
// wave-synchronized.

#define INSERT64(kv) do {                                     \
    ull _kk = (kv);                                           \
    bool _ci = _kk < ad[15];                                  \
    _Pragma("unroll")                                         \
    for (int _u = 15; _u >= 1; --_u) {                        \
      bool _cm = _kk < ad[_u - 1];                            \
      ull _nd = _cm ? ad[_u - 1] : _kk;                       \
      ad[_u] = _ci ? _nd : ad[_u];                            \
      _ci = _cm;                                              \
    }                                                         \
    ad[0] = _ci ? _kk : ad[0];                                \
    thr = ad[15];                                             \
  } while (0)

__global__ __launch_bounds__(512) void knn_kernel(const float4* __restrict__ cpack,
                                                  int* __restrict__ knn) {
  __shared__ ull mk[(NSL - 1) * 16][64];   // 57344 B

  int bid = blockIdx.x;
  int b = bid >> 7;
  int q0 = (bid & 127) << 6;
  int tid = threadIdx.x;
  int q = tid & 63;
  int s = tid >> 6;                        // slice 0..7
  int qg = q0 + q;

  const float4* cp = cpack + (size_t)b * Nn;
  float4 qc = cp[qg];
  float qs = qc.w;
  float qx2 = 2.f * qc.x, qy2 = 2.f * qc.y, qz2 = 2.f * qc.z;

  ull ad[16];
#pragma unroll
  for (int i = 0; i < 16; ++i) ad[i] = ~0ull;
  ull thr = ~0ull;
  unsigned thr_hi = 0xFFFFFFFFu;

  // chunk c covers candidates [c*256 + s*32, +32) for this wave's slice s
  for (int c = 0; c < Nn / (NSL * CH); ++c) {
    int base = c * (NSL * CH) + s * CH;
    const float4* cpb = cp + base;
    unsigned mask = 0;
#pragma unroll 8
    for (int j = 0; j < CH; ++j) {
      float4 c4 = cpb[j];
      // dot2 = 2*((qx*cx + qy*cy) + qz*cz), bit-exact via pre-doubling
      float dot2 = __fadd_rn(__fadd_rn(__fmul_rn(qx2, c4.x), __fmul_rn(qy2, c4.y)),
                             __fmul_rn(qz2, c4.z));
      float d2 = __fsub_rn(__fadd_rn(qs, c4.w), dot2);
      // u32 compare (not float: empty-slot threshold bits are NaN pattern);
      // <= admits boundary ties, flush resolves exactly on u64 key
      mask |= (__float_as_uint(d2) <= thr_hi) ? (1u << j) : 0u;
    }
    // exclude self (d2==0 would always be accepted): clear its bit
    unsigned sj = (unsigned)(qg - base);
    if (sj < 32u) mask &= ~(1u << sj);
    // wave-synchronized rescan flush: max(popcount) iterations, exec-masked
    while (__any(mask)) {
      if (mask) {
        int j = __ffs(mask) - 1;
        mask &= (mask - 1);
        float4 c4 = cpb[j];
        float dot2 = __fadd_rn(__fadd_rn(__fmul_rn(qx2, c4.x), __fmul_rn(qy2, c4.y)),
                               __fmul_rn(qz2, c4.z));
        float d2 = __fsub_rn(__fadd_rn(qs, c4.w), dot2);
        ull key = ((ull)__float_as_uint(d2) << 32) | (unsigned)(base + j);
        if (key < thr) INSERT64(key);
      }
    }
    thr_hi = (unsigned)(thr >> 32);
  }

  // merge the 8 slices per query
  if (s > 0) {
#pragma unroll
    for (int i = 0; i < 16; ++i) mk[(s - 1) * 16 + i][q] = ad[i];
  }
  __syncthreads();
  if (s == 0) {
    for (int t = 0; t < (NSL - 1) * 16; ++t) {
      ull kk = mk[t][q];
      if (kk < thr) INSERT64(kk);
    }
    int* op = knn + (size_t)(b * Nn + qg) * 16;
#pragma unroll
    for (int i = 0; i < 16; ++i) op[i] = (int)(ad[i] & 0xFFFFFFFFull);
  }
}

// ---------------- edge features + GEMM + minmax + channel sums ----------------
// VERBATIM the version that passed in rounds 2/5 (block __syncthreads,
// scalar LDS reads). 1 wave per point (grid-stride). lane = cout.
__global__ __launch_bounds__(256) void edge_kernel(
    const float* __restrict__ xt, const int* __restrict__ knn,
    const float* __restrict__ W, const float* __restrict__ bias,
    float* __restrict__ mnb, float* __restrict__ mxb,
    float* __restrict__ ps1, float* __restrict__ ps2) {
  __shared__ float dlds[4][16][64];   // per-wave diffs
  __shared__ float clds[4][64];       // per-wave center
  __shared__ float r1[4][64], r2[4][64];

  int tid = threadIdx.x;
  int l = tid & 63;
  int w = tid >> 6;

  float w1[64], w2[64];
#pragma unroll
  for (int c = 0; c < 64; ++c) {
    w1[c] = W[c * 64 + l];
    w2[c] = W[(64 + c) * 64 + l];
  }
  float bl = bias[l];
  float s1 = 0.f, s2 = 0.f;

  int wid = blockIdx.x * 4 + w;
  int nw = gridDim.x * 4;
  for (int p = wid; p < Bn * Nn; p += nw) {
    int bb = p >> 13;
    const float* xb = xt + (size_t)bb * Nn * 64;
    float ctr = xt[(size_t)p * 64 + l];
    clds[w][l] = ctr;
    const int* ip = knn + (size_t)p * 16;
#pragma unroll
    for (int j = 0; j < 16; ++j) {
      int nj = ip[j];
      dlds[w][j][l] = xb[(size_t)nj * 64 + l] - ctr;
    }
    __syncthreads();

    float cc = bl;
#pragma unroll
    for (int c = 0; c < 64; ++c) cc = fmaf(clds[w][c], w1[c], cc);

    float mn = 3.0e38f, mx = -3.0e38f;
#pragma unroll
    for (int k = 0; k < 16; ++k) {
      float h = cc;
#pragma unroll
      for (int c = 0; c < 64; ++c) h = fmaf(dlds[w][k][c], w2[c], h);
      mn = fminf(mn, h);
      mx = fmaxf(mx, h);
      s1 += h;
      s2 = fmaf(h, h, s2);
    }
    mnb[(size_t)p * 64 + l] = mn;
    mxb[(size_t)p * 64 + l] = mx;
    __syncthreads();
  }

  r1[w][l] = s1; r2[w][l] = s2;
  __syncthreads();
  if (w == 0) {
    float a = r1[0][l] + r1[1][l] + r1[2][l] + r1[3][l];
    float c2 = r2[0][l] + r2[1][l] + r2[2][l] + r2[3][l];
    ps1[blockIdx.x * 64 + l] = a;
    ps2[blockIdx.x * 64 + l] = c2;
  }
}

// ---------------- deterministic stats reduction ----------------
__global__ __launch_bounds__(256) void stats_kernel(const float* __restrict__ ps1,
                                                    const float* __restrict__ ps2,
                                                    float* __restrict__ stats) {
  __shared__ float r1[4][64], r2[4][64];
  int c = threadIdx.x & 63, g = threadIdx.x >> 6;
  float a = 0.f, b2 = 0.f;
  for (int i = g; i < 512; i += 4) { a += ps1[i * 64 + c]; b2 += ps2[i * 64 + c]; }
  r1[g][c] = a; r2[g][c] = b2;
  __syncthreads();
  if (g == 0) {
    float s1 = r1[0][c] + r1[1][c] + r1[2][c] + r1[3][c];
    float s2 = r2[0][c] + r2[1][c] + r2[2][c] + r2[3][c];
    const float invM = 1.f / 524288.f;  // B*N*K
    float mean = s1 * invM;
    float var = s2 * invM - mean * mean;
    stats[c] = mean;
    stats[64 + c] = var;
  }
}

// ---------------- finalize: normalize+relu+max_k, transposed store ----------------
__global__ __launch_bounds__(256) void final_kernel(
    const float* __restrict__ mnb, const float* __restrict__ mxb,
    const float* __restrict__ stats, const float* __restrict__ gamma,
    const float* __restrict__ beta, float* __restrict__ out) {
  __shared__ float tile[64][65];
  int bid = blockIdx.x;
  int b = bid >> 7;
  int n0 = (bid & 127) << 6;
  int tx = threadIdx.x & 63, ty = threadIdx.x >> 6;
  float mean = stats[tx], var = stats[64 + tx];
  float sc = gamma[tx] * rsqrtf(var + 1e-5f);
  float sh = fmaf(-mean, sc, beta[tx]);
  for (int r = ty; r < 64; r += 4) {
    size_t off = ((size_t)(b * Nn + n0 + r)) * 64 + tx;
    float lo = fmaf(mnb[off], sc, sh);
    float hi = fmaf(mxb[off], sc, sh);
    // max_k relu(sc*h+sh) == max(relu(sc*maxh+sh), relu(sc*minh+sh)) any sc sign
    tile[tx][r] = fmaxf(fmaxf(hi, lo), 0.f);
  }
  __syncthreads();
  for (int r = ty; r < 64; r += 4)
    out[((size_t)b * 64 + r) * Nn + n0 + tx] = tile[r][tx];
}

extern "C" void kernel_launch(void* const* d_in, const int* in_sizes, int n_in,
                              void* d_out, int out_size, void* d_ws, size_t ws_size,
                              hipStream_t stream) {
  const float* x      = (const float*)d_in[0];
  const float* coords = (const float*)d_in[1];
  const float* W      = (const float*)d_in[2];
  const float* bias   = (const float*)d_in[3];
  const float* gamma  = (const float*)d_in[4];
  const float* beta   = (const float*)d_in[5];
  float* out = (float*)d_out;

  char* ws = (char*)d_ws;
  float*  xt    = (float*)ws;
  int*    knn   = (int*)(ws + 8388608);
  float*  mnb   = (float*)(ws + 10485760);
  float4* cpack = (float4*)(ws + 10485760);   // aliases mnb (dead until edge)
  float*  mxb   = (float*)(ws + 18874368);
  float*  ps1   = (float*)(ws + 27262976);
  float*  ps2   = (float*)(ws + 27394048);
  float*  stats = (float*)(ws + 27525120);

  transpose_kernel<<<dim3(512), dim3(256), 0, stream>>>(x, coords, xt, cpack);
  knn_kernel<<<dim3(512), dim3(512), 0, stream>>>(cpack, knn);
  edge_kernel<<<dim3(512), dim3(256), 0, stream>>>(xt, knn, W, bias, mnb, mxb, ps1, ps2);
  stats_kernel<<<dim3(1), dim3(256), 0, stream>>>(ps1, ps2, stats);
  final_kernel<<<dim3(512), dim3(256), 0, stream>>>(mnb, mxb, stats, gamma, beta, out);
}

// Round 8
// 618.284 us; speedup vs baseline: 1.0568x; 1.0568x over previous
//
#include <hip/hip_runtime.h>

// EdgeConv: B=4, C=64, N=8192, K=16, COUT=64, fp32.
// ws layout (27.6 MB, cpack aliased onto mnb):
//   xt    : 0         (B*N*C f32 = 8388608 B)   x transposed to (B,N,C)
//   knn   : 8388608   (B*N*16 i32 = 2097152 B)
//   mnb   : 10485760  (B*N*64 f32 = 8388608 B)  min_k h   [cpack aliases here first]
//   mxb   : 18874368  (B*N*64 f32 = 8388608 B)  max_k h
//   ps1   : 27262976  (512*64 f32)
//   ps2   : 27394048  (512*64 f32)
//   stats : 27525120  (128 f32)

#define Bn 4
#define Cn 64
#define Nn 8192
#define Kn 16
#define NSL 8   // slices per query

typedef unsigned long long ull;

// ------- transpose x (B,C,N) -> xt (B,N,C); also pack coords -> (x,y,z,sq) -------
__global__ __launch_bounds__(256) void transpose_kernel(const float* __restrict__ x,
                                                        const float* __restrict__ coords,
                                                        float* __restrict__ xt,
                                                        float4* __restrict__ cpack) {
  __shared__ float tile[64][65];
  int bid = blockIdx.x;          // 512 = B * (N/64)
  int b = bid >> 7;
  int n0 = (bid & 127) << 6;
  int tx = threadIdx.x & 63;
  int ty = threadIdx.x >> 6;
  for (int c = ty; c < 64; c += 4)
    tile[tx][c] = x[((size_t)b * 64 + c) * Nn + n0 + tx];
  if (ty == 0) {
    int n = n0 + tx;
    const float* cb = coords + (size_t)b * 3 * Nn;
    float cx = cb[n], cy = cb[Nn + n], cz = cb[2 * Nn + n];
    // sq exactly as np.sum(ct*ct,-1): ((x*x + y*y) + z*z), no FMA
    float cs = __fadd_rn(__fadd_rn(__fmul_rn(cx, cx), __fmul_rn(cy, cy)),
                         __fmul_rn(cz, cz));
    cpack[(size_t)b * Nn + n] = make_float4(cx, cy, cz, cs);
  }
  __syncthreads();
  for (int r = ty; r < 64; r += 4)
    xt[((size_t)b * Nn + n0 + r) * 64 + tx] = tile[r][tx];
}

// ---------------- brute-force KNN (top-16 excluding self) ----------------
// d2 EXACTLY like the reference: (sq_n + sq_m) - 2*dot, non-contracted f32
// (2*dot via pre-doubled query coords: pow2 scale commutes with rounding).
// Key = (f32_bits(d2)<<32)|idx: stable lowest-index tie-break like lax.top_k.
// Self excluded by clearing its mask bit. Top-16 kept UNSORTED via
// replace-max (keys always distinct -> exactly one slot equals max):
// parallel 16-way cndmask + 4-deep max tree, no serial shift chain.
// Set of 16 smallest u64 keys is insertion-order-invariant; downstream is
// order-invariant -> semantics identical to the r5/r7 passing kernels.
//
// 512 blocks = B*(N/64); 512 threads = 64 queries x 8 slices. Candidates
// staged in LDS (512 float4/round, aliased onto the merge buffer); hot loop
// = broadcast ds_read_b128 + 7 exact VALU + cmp -> accept bit in u32 mask.
// Rare wave-synchronized rescan flush recomputes d2 bit-identically.

#define RMAX(kv) do {                                         \
    ull _kk = (kv);                                           \
    _Pragma("unroll")                                         \
    for (int _u = 0; _u < 16; ++_u)                           \
      ad[_u] = (ad[_u] == thr) ? _kk : ad[_u];                \
    ull _t0 = ad[0] > ad[1] ? ad[0] : ad[1];                  \
    ull _t1 = ad[2] > ad[3] ? ad[2] : ad[3];                  \
    ull _t2 = ad[4] > ad[5] ? ad[4] : ad[5];                  \
    ull _t3 = ad[6] > ad[7] ? ad[6] : ad[7];                  \
    ull _t4 = ad[8] > ad[9] ? ad[8] : ad[9];                  \
    ull _t5 = ad[10] > ad[11] ? ad[10] : ad[11];              \
    ull _t6 = ad[12] > ad[13] ? ad[12] : ad[13];              \
    ull _t7 = ad[14] > ad[15] ? ad[14] : ad[15];              \
    ull _u0 = _t0 > _t1 ? _t0 : _t1;                          \
    ull _u1 = _t2 > _t3 ? _t2 : _t3;                          \
    ull _u2 = _t4 > _t5 ? _t4 : _t5;                          \
    ull _u3 = _t6 > _t7 ? _t6 : _t7;                          \
    ull _v0 = _u0 > _u1 ? _u0 : _u1;                          \
    ull _v1 = _u2 > _u3 ? _u2 : _u3;                          \
    thr = _v0 > _v1 ? _v0 : _v1;                              \
  } while (0)

__global__ __launch_bounds__(512) void knn_kernel(const float4* __restrict__ cpack,
                                                  int* __restrict__ knn) {
  __shared__ __align__(16) ull mk[(NSL - 1) * 16 * 64];  // 57344 B; stage aliases
  float4* stage = (float4*)mk;                            // 512 float4 = 8 KB

  int bid = blockIdx.x;
  int b = bid >> 7;
  int q0 = (bid & 127) << 6;
  int tid = threadIdx.x;
  int q = tid & 63;
  int s = tid >> 6;                        // slice 0..7
  int qg = q0 + q;

  const float4* cp = cpack + (size_t)b * Nn;
  float4 qc = cp[qg];
  float qs = qc.w;
  float qx2 = 2.f * qc.x, qy2 = 2.f * qc.y, qz2 = 2.f * qc.z;

  ull ad[16];
#pragma unroll
  for (int i = 0; i < 16; ++i) ad[i] = 0xFFFFFFFF00000000ull | (unsigned)i;
  ull thr = 0xFFFFFFFF0000000Full;
  unsigned thr_hi = 0xFFFFFFFFu;

  for (int t = 0; t < Nn / 512; ++t) {     // 16 staging rounds
    __syncthreads();                        // prev round's readers done
    stage[tid] = cp[t * 512 + tid];
    __syncthreads();                        // stage visible
#pragma unroll
    for (int half = 0; half < 2; ++half) {
      int loc = half * 256 + s * 32;        // LDS-local window base
      int base = t * 512 + loc;             // global candidate base
      unsigned mask = 0;
#pragma unroll 8
      for (int j = 0; j < 32; ++j) {
        float4 c4 = stage[loc + j];
        // dot2 = 2*((qx*cx + qy*cy) + qz*cz), bit-exact via pre-doubling
        float dot2 = __fadd_rn(__fadd_rn(__fmul_rn(qx2, c4.x), __fmul_rn(qy2, c4.y)),
                               __fmul_rn(qz2, c4.z));
        float d2 = __fsub_rn(__fadd_rn(qs, c4.w), dot2);
        // u32 compare (empty-slot threshold bits are NaN pattern);
        // <= admits boundary ties, flush resolves exactly on u64 key
        mask |= (__float_as_uint(d2) <= thr_hi) ? (1u << j) : 0u;
      }
      // exclude self (d2==0 would always be accepted)
      unsigned sj = (unsigned)(qg - base);
      if (sj < 32u) mask &= ~(1u << sj);
      // wave-synchronized rescan flush
      while (__any(mask)) {
        if (mask) {
          int j = __ffs(mask) - 1;
          mask &= (mask - 1);
          float4 c4 = stage[loc + j];
          float dot2 = __fadd_rn(__fadd_rn(__fmul_rn(qx2, c4.x), __fmul_rn(qy2, c4.y)),
                                 __fmul_rn(qz2, c4.z));
          float d2 = __fsub_rn(__fadd_rn(qs, c4.w), dot2);
          ull key = ((ull)__float_as_uint(d2) << 32) | (unsigned)(base + j);
          if (key < thr) RMAX(key);
        }
      }
      thr_hi = (unsigned)(thr >> 32);
    }
  }

  // merge the 8 slices per query (mk reuses stage memory)
  __syncthreads();                          // all waves done reading stage
  if (s > 0) {
#pragma unroll
    for (int i = 0; i < 16; ++i) mk[(((s - 1) << 4) + i) * 64 + q] = ad[i];
  }
  __syncthreads();
  if (s == 0) {
    for (int t = 0; t < (NSL - 1) * 16; ++t) {
      ull kk = mk[t * 64 + q];
      if (kk < thr) RMAX(kk);
    }
    int* op = knn + (size_t)(b * Nn + qg) * 16;
#pragma unroll
    for (int i = 0; i < 16; ++i) op[i] = (int)(ad[i] & 0xFFFFFFFFull);
  }
}

// ---------------- edge features + GEMM + minmax + channel sums ----------------
// VERBATIM the version that passed in rounds 2/5/7.
__global__ __launch_bounds__(256) void edge_kernel(
    const float* __restrict__ xt, const int* __restrict__ knn,
    const float* __restrict__ W, const float* __restrict__ bias,
    float* __restrict__ mnb, float* __restrict__ mxb,
    float* __restrict__ ps1, float* __restrict__ ps2) {
  __shared__ float dlds[4][16][64];   // per-wave diffs
  __shared__ float clds[4][64];       // per-wave center
  __shared__ float r1[4][64], r2[4][64];

  int tid = threadIdx.x;
  int l = tid & 63;
  int w = tid >> 6;

  float w1[64], w2[64];
#pragma unroll
  for (int c = 0; c < 64; ++c) {
    w1[c] = W[c * 64 + l];
    w2[c] = W[(64 + c) * 64 + l];
  }
  float bl = bias[l];
  float s1 = 0.f, s2 = 0.f;

  int wid = blockIdx.x * 4 + w;
  int nw = gridDim.x * 4;
  for (int p = wid; p < Bn * Nn; p += nw) {
    int bb = p >> 13;
    const float* xb = xt + (size_t)bb * Nn * 64;
    float ctr = xt[(size_t)p * 64 + l];
    clds[w][l] = ctr;
    const int* ip = knn + (size_t)p * 16;
#pragma unroll
    for (int j = 0; j < 16; ++j) {
      int nj = ip[j];
      dlds[w][j][l] = xb[(size_t)nj * 64 + l] - ctr;
    }
    __syncthreads();

    float cc = bl;
#pragma unroll
    for (int c = 0; c < 64; ++c) cc = fmaf(clds[w][c], w1[c], cc);

    float mn = 3.0e38f, mx = -3.0e38f;
#pragma unroll
    for (int k = 0; k < 16; ++k) {
      float h = cc;
#pragma unroll
      for (int c = 0; c < 64; ++c) h = fmaf(dlds[w][k][c], w2[c], h);
      mn = fminf(mn, h);
      mx = fmaxf(mx, h);
      s1 += h;
      s2 = fmaf(h, h, s2);
    }
    mnb[(size_t)p * 64 + l] = mn;
    mxb[(size_t)p * 64 + l] = mx;
    __syncthreads();
  }

  r1[w][l] = s1; r2[w][l] = s2;
  __syncthreads();
  if (w == 0) {
    float a = r1[0][l] + r1[1][l] + r1[2][l] + r1[3][l];
    float c2 = r2[0][l] + r2[1][l] + r2[2][l] + r2[3][l];
    ps1[blockIdx.x * 64 + l] = a;
    ps2[blockIdx.x * 64 + l] = c2;
  }
}

// ---------------- deterministic stats reduction ----------------
__global__ __launch_bounds__(256) void stats_kernel(const float* __restrict__ ps1,
                                                    const float* __restrict__ ps2,
                                                    float* __restrict__ stats) {
  __shared__ float r1[4][64], r2[4][64];
  int c = threadIdx.x & 63, g = threadIdx.x >> 6;
  float a = 0.f, b2 = 0.f;
  for (int i = g; i < 512; i += 4) { a += ps1[i * 64 + c]; b2 += ps2[i * 64 + c]; }
  r1[g][c] = a; r2[g][c] = b2;
  __syncthreads();
  if (g == 0) {
    float s1 = r1[0][c] + r1[1][c] + r1[2][c] + r1[3][c];
    float s2 = r2[0][c] + r2[1][c] + r2[2][c] + r2[3][c];
    const float invM = 1.f / 524288.f;  // B*N*K
    float mean = s1 * invM;
    float var = s2 * invM - mean * mean;
    stats[c] = mean;
    stats[64 + c] = var;
  }
}

// ---------------- finalize: normalize+relu+max_k, transposed store ----------------
__global__ __launch_bounds__(256) void final_kernel(
    const float* __restrict__ mnb, const float* __restrict__ mxb,
    const float* __restrict__ stats, const float* __restrict__ gamma,
    const float* __restrict__ beta, float* __restrict__ out) {
  __shared__ float tile[64][65];
  int bid = blockIdx.x;
  int b = bid >> 7;
  int n0 = (bid & 127) << 6;
  int tx = threadIdx.x & 63, ty = threadIdx.x >> 6;
  float mean = stats[tx], var = stats[64 + tx];
  float sc = gamma[tx] * rsqrtf(var + 1e-5f);
  float sh = fmaf(-mean, sc, beta[tx]);
  for (int r = ty; r < 64; r += 4) {
    size_t off = ((size_t)(b * Nn + n0 + r)) * 64 + tx;
    float lo = fmaf(mnb[off], sc, sh);
    float hi = fmaf(mxb[off], sc, sh);
    // max_k relu(sc*h+sh) == max(relu(sc*maxh+sh), relu(sc*minh+sh)) any sc sign
    tile[tx][r] = fmaxf(fmaxf(hi, lo), 0.f);
  }
  __syncthreads();
  for (int r = ty; r < 64; r += 4)
    out[((size_t)b * 64 + r) * Nn + n0 + tx] = tile[r][tx];
}

extern "C" void kernel_launch(void* const* d_in, const int* in_sizes, int n_in,
                              void* d_out, int out_size, void* d_ws, size_t ws_size,
                              hipStream_t stream) {
  const float* x      = (const float*)d_in[0];
  const float* coords = (const float*)d_in[1];
  const float* W      = (const float*)d_in[2];
  const float* bias   = (const float*)d_in[3];
  const float* gamma  = (const float*)d_in[4];
  const float* beta   = (const float*)d_in[5];
  float* out = (float*)d_out;

  char* ws = (char*)d_ws;
  float*  xt    = (float*)ws;
  int*    knn   = (int*)(ws + 8388608);
  float*  mnb   = (float*)(ws + 10485760);
  float4* cpack = (float4*)(ws + 10485760);   // aliases mnb (dead until edge)
  float*  mxb   = (float*)(ws + 18874368);
  float*  ps1   = (float*)(ws + 27262976);
  float*  ps2   = (float*)(ws + 27394048);
  float*  stats = (float*)(ws + 27525120);

  transpose_kernel<<<dim3(512), dim3(256), 0, stream>>>(x, coords, xt, cpack);
  knn_kernel<<<dim3(512), dim3(512), 0, stream>>>(cpack, knn);
  edge_kernel<<<dim3(512), dim3(256), 0, stream>>>(xt, knn, W, bias, mnb, mxb, ps1, ps2);
  stats_kernel<<<dim3(1), dim3(256), 0, stream>>>(ps1, ps2, stats);
  final_kernel<<<dim3(512), dim3(256), 0, stream>>>(mnb, mxb, stats, gamma, beta, out);
}

// Round 9
// 576.099 us; speedup vs baseline: 1.1341x; 1.0732x over previous
//
#include <hip/hip_runtime.h>

// EdgeConv: B=4, C=64, N=8192, K=16, COUT=64, fp32.
// ws layout (27.6 MB, cpack aliased onto mnb):
//   xt    : 0         (B*N*C f32 = 8388608 B)   x transposed to (B,N,C)
//   knn   : 8388608   (B*N*16 i32 = 2097152 B)
//   mnb   : 10485760  (B*N*64 f32 = 8388608 B)  min_k h   [cpack aliases here first]
//   mxb   : 18874368  (B*N*64 f32 = 8388608 B)  max_k h
//   ps1   : 27262976  (512*64 f32)
//   ps2   : 27394048  (512*64 f32)
//   stats : 27525120  (128 f32)

#define Bn 4
#define Cn 64
#define Nn 8192
#define Kn 16
#define NSL 8   // slices per query

typedef unsigned long long ull;

// ------- transpose x (B,C,N) -> xt (B,N,C); also pack coords -> (x,y,z,sq) -------
__global__ __launch_bounds__(256) void transpose_kernel(const float* __restrict__ x,
                                                        const float* __restrict__ coords,
                                                        float* __restrict__ xt,
                                                        float4* __restrict__ cpack) {
  __shared__ float tile[64][65];
  int bid = blockIdx.x;          // 512 = B * (N/64)
  int b = bid >> 7;
  int n0 = (bid & 127) << 6;
  int tx = threadIdx.x & 63;
  int ty = threadIdx.x >> 6;
  for (int c = ty; c < 64; c += 4)
    tile[tx][c] = x[((size_t)b * 64 + c) * Nn + n0 + tx];
  if (ty == 0) {
    int n = n0 + tx;
    const float* cb = coords + (size_t)b * 3 * Nn;
    float cx = cb[n], cy = cb[Nn + n], cz = cb[2 * Nn + n];
    // sq exactly as np.sum(ct*ct,-1): ((x*x + y*y) + z*z), no FMA
    float cs = __fadd_rn(__fadd_rn(__fmul_rn(cx, cx), __fmul_rn(cy, cy)),
                         __fmul_rn(cz, cz));
    cpack[(size_t)b * Nn + n] = make_float4(cx, cy, cz, cs);
  }
  __syncthreads();
  for (int r = ty; r < 64; r += 4)
    xt[((size_t)b * Nn + n0 + r) * 64 + tx] = tile[r][tx];
}

// ---------------- brute-force KNN (top-16 excluding self) ----------------
// d2 EXACTLY like the reference: (sq_n + sq_m) - 2*dot, non-contracted f32
// (2*dot via pre-doubled query coords: pow2 scale commutes with rounding).
// Key = (f32_bits(d2)<<32)|idx: stable lowest-index tie-break like lax.top_k.
// Self excluded by clearing its mask bit. Top-16 kept UNSORTED via
// replace-max (keys distinct -> exactly one slot equals max).
//
// NEW (r9): shared per-query accept threshold across the 8 slice-waves.
// sthr[q] = min over waves of (hi-32 bits of that wave's 16th-best key).
// Valid filter: any wave's local 16th >= query's final global 16th, so
// min over waves >= final 16th; every true top-16 member passes (<= test
// admits hi-bit ties; exact u64 resolution in RMAX/merge); stale reads
// only loosen. Cuts per-lane accept rate ~8x after warmup -> far fewer
// wave-synchronized flush iterations (the measured VALU hog).

#define RMAX(kv) do {                                         \
    ull _kk = (kv);                                           \
    _Pragma("unroll")                                         \
    for (int _u = 0; _u < 16; ++_u)                           \
      ad[_u] = (ad[_u] == thr) ? _kk : ad[_u];                \
    ull _t0 = ad[0] > ad[1] ? ad[0] : ad[1];                  \
    ull _t1 = ad[2] > ad[3] ? ad[2] : ad[3];                  \
    ull _t2 = ad[4] > ad[5] ? ad[4] : ad[5];                  \
    ull _t3 = ad[6] > ad[7] ? ad[6] : ad[7];                  \
    ull _t4 = ad[8] > ad[9] ? ad[8] : ad[9];                  \
    ull _t5 = ad[10] > ad[11] ? ad[10] : ad[11];              \
    ull _t6 = ad[12] > ad[13] ? ad[12] : ad[13];              \
    ull _t7 = ad[14] > ad[15] ? ad[14] : ad[15];              \
    ull _u0 = _t0 > _t1 ? _t0 : _t1;                          \
    ull _u1 = _t2 > _t3 ? _t2 : _t3;                          \
    ull _u2 = _t4 > _t5 ? _t4 : _t5;                          \
    ull _u3 = _t6 > _t7 ? _t6 : _t7;                          \
    ull _v0 = _u0 > _u1 ? _u0 : _u1;                          \
    ull _v1 = _u2 > _u3 ? _u2 : _u3;                          \
    thr = _v0 > _v1 ? _v0 : _v1;                              \
  } while (0)

__global__ __launch_bounds__(512) void knn_kernel(const float4* __restrict__ cpack,
                                                  int* __restrict__ knn) {
  __shared__ __align__(16) ull mk[(NSL - 1) * 16 * 64];  // 57344 B; stage aliases
  float4* stage = (float4*)mk;                            // 512 float4 = 8 KB
  __shared__ unsigned sthr[64];                           // shared per-query thr

  int bid = blockIdx.x;
  int b = bid >> 7;
  int q0 = (bid & 127) << 6;
  int tid = threadIdx.x;
  int q = tid & 63;
  int s = tid >> 6;                        // slice 0..7
  int qg = q0 + q;

  const float4* cp = cpack + (size_t)b * Nn;
  float4 qc = cp[qg];
  float qs = qc.w;
  float qx2 = 2.f * qc.x, qy2 = 2.f * qc.y, qz2 = 2.f * qc.z;

  if (tid < 64) sthr[tid] = 0xFFFFFFFFu;   // visible after first __syncthreads

  ull ad[16];
#pragma unroll
  for (int i = 0; i < 16; ++i) ad[i] = 0xFFFFFFFF00000000ull | (unsigned)i;
  ull thr = 0xFFFFFFFF0000000Full;
  unsigned thr_hi = 0xFFFFFFFFu;

  for (int t = 0; t < Nn / 512; ++t) {     // 16 staging rounds
    __syncthreads();                        // prev round's readers done
    stage[tid] = cp[t * 512 + tid];
    __syncthreads();                        // stage (and t=0: sthr init) visible
#pragma unroll
    for (int half = 0; half < 2; ++half) {
      int loc = half * 256 + s * 32;        // LDS-local window base
      int base = t * 512 + loc;             // global candidate base
      // refresh accept filter from shared threshold (monotone decreasing,
      // always >= final global 16th -> conservative)
      unsigned sh = sthr[q];
      thr_hi = sh < thr_hi ? sh : thr_hi;
      unsigned mask = 0;
#pragma unroll 8
      for (int j = 0; j < 32; ++j) {
        float4 c4 = stage[loc + j];
        // dot2 = 2*((qx*cx + qy*cy) + qz*cz), bit-exact via pre-doubling
        float dot2 = __fadd_rn(__fadd_rn(__fmul_rn(qx2, c4.x), __fmul_rn(qy2, c4.y)),
                               __fmul_rn(qz2, c4.z));
        float d2 = __fsub_rn(__fadd_rn(qs, c4.w), dot2);
        // u32 compare (empty-slot threshold bits are NaN pattern);
        // <= admits boundary ties, flush resolves exactly on u64 key
        mask |= (__float_as_uint(d2) <= thr_hi) ? (1u << j) : 0u;
      }
      // exclude self (d2==0 would always be accepted)
      unsigned sj = (unsigned)(qg - base);
      if (sj < 32u) mask &= ~(1u << sj);
      // wave-synchronized rescan flush
      while (__any(mask)) {
        if (mask) {
          int j = __ffs(mask) - 1;
          mask &= (mask - 1);
          float4 c4 = stage[loc + j];
          float dot2 = __fadd_rn(__fadd_rn(__fmul_rn(qx2, c4.x), __fmul_rn(qy2, c4.y)),
                                 __fmul_rn(qz2, c4.z));
          float d2 = __fsub_rn(__fadd_rn(qs, c4.w), dot2);
          ull key = ((ull)__float_as_uint(d2) << 32) | (unsigned)(base + j);
          if (key < thr) RMAX(key);
        }
      }
      // publish tightened local threshold; filter refresh happens next chunk
      unsigned lh = (unsigned)(thr >> 32);
      thr_hi = lh < thr_hi ? lh : thr_hi;
      atomicMin(&sthr[q], lh);
    }
  }

  // merge the 8 slices per query (mk reuses stage memory)
  __syncthreads();                          // all waves done reading stage
  if (s > 0) {
#pragma unroll
    for (int i = 0; i < 16; ++i) mk[(((s - 1) << 4) + i) * 64 + q] = ad[i];
  }
  __syncthreads();
  if (s == 0) {
    for (int t = 0; t < (NSL - 1) * 16; ++t) {
      ull kk = mk[t * 64 + q];
      if (kk < thr) RMAX(kk);
    }
    int* op = knn + (size_t)(b * Nn + qg) * 16;
#pragma unroll
    for (int i = 0; i < 16; ++i) op[i] = (int)(ad[i] & 0xFFFFFFFFull);
  }
}

// ---------------- edge features + GEMM + minmax + channel sums ----------------
// VERBATIM the version that passed in rounds 2/5/7/8.
__global__ __launch_bounds__(256) void edge_kernel(
    const float* __restrict__ xt, const int* __restrict__ knn,
    const float* __restrict__ W, const float* __restrict__ bias,
    float* __restrict__ mnb, float* __restrict__ mxb,
    float* __restrict__ ps1, float* __restrict__ ps2) {
  __shared__ float dlds[4][16][64];   // per-wave diffs
  __shared__ float clds[4][64];       // per-wave center
  __shared__ float r1[4][64], r2[4][64];

  int tid = threadIdx.x;
  int l = tid & 63;
  int w = tid >> 6;

  float w1[64], w2[64];
#pragma unroll
  for (int c = 0; c < 64; ++c) {
    w1[c] = W[c * 64 + l];
    w2[c] = W[(64 + c) * 64 + l];
  }
  float bl = bias[l];
  float s1 = 0.f, s2 = 0.f;

  int wid = blockIdx.x * 4 + w;
  int nw = gridDim.x * 4;
  for (int p = wid; p < Bn * Nn; p += nw) {
    int bb = p >> 13;
    const float* xb = xt + (size_t)bb * Nn * 64;
    float ctr = xt[(size_t)p * 64 + l];
    clds[w][l] = ctr;
    const int* ip = knn + (size_t)p * 16;
#pragma unroll
    for (int j = 0; j < 16; ++j) {
      int nj = ip[j];
      dlds[w][j][l] = xb[(size_t)nj * 64 + l] - ctr;
    }
    __syncthreads();

    float cc = bl;
#pragma unroll
    for (int c = 0; c < 64; ++c) cc = fmaf(clds[w][c], w1[c], cc);

    float mn = 3.0e38f, mx = -3.0e38f;
#pragma unroll
    for (int k = 0; k < 16; ++k) {
      float h = cc;
#pragma unroll
      for (int c = 0; c < 64; ++c) h = fmaf(dlds[w][k][c], w2[c], h);
      mn = fminf(mn, h);
      mx = fmaxf(mx, h);
      s1 += h;
      s2 = fmaf(h, h, s2);
    }
    mnb[(size_t)p * 64 + l] = mn;
    mxb[(size_t)p * 64 + l] = mx;
    __syncthreads();
  }

  r1[w][l] = s1; r2[w][l] = s2;
  __syncthreads();
  if (w == 0) {
    float a = r1[0][l] + r1[1][l] + r1[2][l] + r1[3][l];
    float c2 = r2[0][l] + r2[1][l] + r2[2][l] + r2[3][l];
    ps1[blockIdx.x * 64 + l] = a;
    ps2[blockIdx.x * 64 + l] = c2;
  }
}

// ---------------- deterministic stats reduction ----------------
__global__ __launch_bounds__(256) void stats_kernel(const float* __restrict__ ps1,
                                                    const float* __restrict__ ps2,
                                                    float* __restrict__ stats) {
  __shared__ float r1[4][64], r2[4][64];
  int c = threadIdx.x & 63, g = threadIdx.x >> 6;
  float a = 0.f, b2 = 0.f;
  for (int i = g; i < 512; i += 4) { a += ps1[i * 64 + c]; b2 += ps2[i * 64 + c]; }
  r1[g][c] = a; r2[g][c] = b2;
  __syncthreads();
  if (g == 0) {
    float s1 = r1[0][c] + r1[1][c] + r1[2][c] + r1[3][c];
    float s2 = r2[0][c] + r2[1][c] + r2[2][c] + r2[3][c];
    const float invM = 1.f / 524288.f;  // B*N*K
    float mean = s1 * invM;
    float var = s2 * invM - mean * mean;
    stats[c] = mean;
    stats[64 + c] = var;
  }
}

// ---------------- finalize: normalize+relu+max_k, transposed store ----------------
__global__ __launch_bounds__(256) void final_kernel(
    const float* __restrict__ mnb, const float* __restrict__ mxb,
    const float* __restrict__ stats, const float* __restrict__ gamma,
    const float* __restrict__ beta, float* __restrict__ out) {
  __shared__ float tile[64][65];
  int bid = blockIdx.x;
  int b = bid >> 7;
  int n0 = (bid & 127) << 6;
  int tx = threadIdx.x & 63, ty = threadIdx.x >> 6;
  float mean = stats[tx], var = stats[64 + tx];
  float sc = gamma[tx] * rsqrtf(var + 1e-5f);
  float sh = fmaf(-mean, sc, beta[tx]);
  for (int r = ty; r < 64; r += 4) {
    size_t off = ((size_t)(b * Nn + n0 + r)) * 64 + tx;
    float lo = fmaf(mnb[off], sc, sh);
    float hi = fmaf(mxb[off], sc, sh);
    // max_k relu(sc*h+sh) == max(relu(sc*maxh+sh), relu(sc*minh+sh)) any sc sign
    tile[tx][r] = fmaxf(fmaxf(hi, lo), 0.f);
  }
  __syncthreads();
  for (int r = ty; r < 64; r += 4)
    out[((size_t)b * 64 + r) * Nn + n0 + tx] = tile[r][tx];
}

extern "C" void kernel_launch(void* const* d_in, const int* in_sizes, int n_in,
                              void* d_out, int out_size, void* d_ws, size_t ws_size,
                              hipStream_t stream) {
  const float* x      = (const float*)d_in[0];
  const float* coords = (const float*)d_in[1];
  const float* W      = (const float*)d_in[2];
  const float* bias   = (const float*)d_in[3];
  const float* gamma  = (const float*)d_in[4];
  const float* beta   = (const float*)d_in[5];
  float* out = (float*)d_out;

  char* ws = (char*)d_ws;
  float*  xt    = (float*)ws;
  int*    knn   = (int*)(ws + 8388608);
  float*  mnb   = (float*)(ws + 10485760);
  float4* cpack = (float4*)(ws + 10485760);   // aliases mnb (dead until edge)
  float*  mxb   = (float*)(ws + 18874368);
  float*  ps1   = (float*)(ws + 27262976);
  float*  ps2   = (float*)(ws + 27394048);
  float*  stats = (float*)(ws + 27525120);

  transpose_kernel<<<dim3(512), dim3(256), 0, stream>>>(x, coords, xt, cpack);
  knn_kernel<<<dim3(512), dim3(512), 0, stream>>>(cpack, knn);
  edge_kernel<<<dim3(512), dim3(256), 0, stream>>>(xt, knn, W, bias, mnb, mxb, ps1, ps2);
  stats_kernel<<<dim3(1), dim3(256), 0, stream>>>(ps1, ps2, stats);
  final_kernel<<<dim3(512), dim3(256), 0, stream>>>(mnb, mxb, stats, gamma, beta, out);
}